// Round 7
// baseline (158.509 us; speedup 1.0000x reference)
//
#include <hip/hip_runtime.h>

// B=4, S=1024, H=16, D=64 attention, clipped softmax.
// Round 7 = Round 5/6 barrier-free streaming MFMA kernel, but with the
// register double-buffer pipeline FORCED via inline asm:
//   - global_load_dwordx4 (saddr form) issued as volatile asm -> compiler
//     cannot sink the loads next to their uses (r6 failure mode, VGPR=88).
//   - s_waitcnt vmcnt(0) as volatile asm with the 8 dest fragments as "+v"
//     operands -> consumers are data-dependent on the wait, can't hoist.
// Each load batch gets one full compute step (~270 cyc) to cover L2 latency.
#define BB 4
#define SS 1024
#define HH 16
#define DD 64

typedef short bf16x8 __attribute__((ext_vector_type(8)));
typedef float f32x4 __attribute__((ext_vector_type(4)));

__device__ __forceinline__ unsigned pk2(float a, float b) {   // pack 2 bf16
    unsigned ua = __float_as_uint(a) + 0x8000u;
    unsigned ub = __float_as_uint(b) + 0x8000u;
    return (ub & 0xffff0000u) | (ua >> 16);
}
__device__ __forceinline__ unsigned short f2bf(float a) {
    return (unsigned short)((__float_as_uint(a) + 0x8000u) >> 16);
}
__device__ __forceinline__ f32x4 mfma16(bf16x8 a, bf16x8 b, f32x4 c) {
    return __builtin_amdgcn_mfma_f32_16x16x32_bf16(a, b, c, 0, 0, 0);
}
// sigma within 32-key chunks (verified r4/r5): pos x holds key ((q^(b>>1))<<3)|(a<<2)|b
__device__ __forceinline__ int sig5(int x) {
    int a = (x >> 4) & 1, qs = (x >> 2) & 3, b2 = x & 3;
    return ((qs ^ (b2 >> 1)) << 3) | (a << 2) | b2;
}

// ---------------- prep: K -> kws (sigma rows), V -> vws (V^T) ----------------
__global__ __launch_bounds__(256)
void prep_kernel(const float* __restrict__ k, const float* __restrict__ v,
                 unsigned short* __restrict__ kws, unsigned short* __restrict__ vws) {
    __shared__ unsigned short sT[64 * 136];
    const int t = threadIdx.x;
    const int bx = blockIdx.x;
    if (bx < 512) {
        const int bh = bx & 63, st = bx >> 6;
        const int h = bh & 15, b = bh >> 4;
        const int row = t >> 1, half = t & 1;
        const int p = st * 128 + row;
        const int key = (p & ~31) | sig5(p & 31);
        const float4* src = (const float4*)k + (((size_t)(b * SS + key) * HH + h) * 16) + half * 8;
        float4 r[8];
        #pragma unroll
        for (int i = 0; i < 8; ++i) r[i] = src[i];
        uint4* dst = (uint4*)(kws + (size_t)(bh * SS + p) * 64 + half * 32);
        #pragma unroll
        for (int u = 0; u < 4; ++u) {
            uint4 val;
            val.x = pk2(r[2*u].x, r[2*u].y);
            val.y = pk2(r[2*u].z, r[2*u].w);
            val.z = pk2(r[2*u+1].x, r[2*u+1].y);
            val.w = pk2(r[2*u+1].z, r[2*u+1].w);
            dst[u] = val;
        }
    } else {
        const int bx2 = bx - 512;
        const int bh = bx2 & 63, st = bx2 >> 6;
        const int h = bh & 15, b = bh >> 4;
        const int o = t >> 4, vc = t & 15;
        const float4* src = (const float4*)v + (((size_t)(b * SS + st * 128 + o * 8) * HH + h) * 16) + vc;
        float4 r[8];
        #pragma unroll
        for (int i = 0; i < 8; ++i) r[i] = src[(size_t)i * HH * 16];
        const float* fr = (const float*)r;
        #pragma unroll
        for (int c = 0; c < 4; ++c) {
            uint4 val;
            val.x = pk2(fr[0*4+c], fr[1*4+c]);
            val.y = pk2(fr[2*4+c], fr[3*4+c]);
            val.z = pk2(fr[4*4+c], fr[5*4+c]);
            val.w = pk2(fr[6*4+c], fr[7*4+c]);
            *(uint4*)&sT[(vc * 4 + c) * 136 + o * 8] = val;
        }
        __syncthreads();
        const int d = t >> 2, part = t & 3;
        uint4* dst = (uint4*)(vws + (size_t)(bh * 64 + d) * SS + st * 128 + part * 32);
        #pragma unroll
        for (int i = 0; i < 4; ++i)
            dst[i] = *(const uint4*)&sT[d * 136 + part * 32 + i * 8];
    }
}

// issue 8 in-flight b128 loads for one 32-key step (volatile: cannot be sunk)
#define ISSUE_KV(K0,K1,K2,K3,V0,V1,V2,V3, vk, vv)                                            \
  asm volatile("global_load_dwordx4 %0, %1, %2 offset:0"    : "=v"(K0) : "v"(vk), "s"(kb));  \
  asm volatile("global_load_dwordx4 %0, %1, %2 offset:64"   : "=v"(K1) : "v"(vk), "s"(kb));  \
  asm volatile("global_load_dwordx4 %0, %1, %2 offset:2048" : "=v"(K2) : "v"(vk), "s"(kb));  \
  asm volatile("global_load_dwordx4 %0, %1, %2 offset:2112" : "=v"(K3) : "v"(vk), "s"(kb));  \
  asm volatile("global_load_dwordx4 %0, %1, %2 offset:0"    : "=v"(V0) : "v"(vv), "s"(vb0)); \
  asm volatile("global_load_dwordx4 %0, %1, %2 offset:0"    : "=v"(V1) : "v"(vv), "s"(vb1)); \
  asm volatile("global_load_dwordx4 %0, %1, %2 offset:0"    : "=v"(V2) : "v"(vv), "s"(vb2)); \
  asm volatile("global_load_dwordx4 %0, %1, %2 offset:0"    : "=v"(V3) : "v"(vv), "s"(vb3));

// drain the batch; "+v" ties make every consumer data-dependent on this wait
#define WAIT_KV(K0,K1,K2,K3,V0,V1,V2,V3)                                  \
  asm volatile("s_waitcnt vmcnt(0)"                                       \
    : "+v"(K0),"+v"(K1),"+v"(K2),"+v"(K3),                                \
      "+v"(V0),"+v"(V1),"+v"(V2),"+v"(V3));

// compute one 32-key step: QK^T -> exp -> PV (all in registers)
__device__ __forceinline__ void step32v(bf16x8 K0, bf16x8 K1, bf16x8 K2, bf16x8 K3,
                                        bf16x8 V0, bf16x8 V1, bf16x8 V2, bf16x8 V3,
                                        const bf16x8 qf[2][2],
                                        f32x4 oacc[2][4], float su[2]) {
    const f32x4 zero = {0.f, 0.f, 0.f, 0.f};
    const float LOG2E = 1.44269504f;
    f32x4 S[2][2];
    S[0][0] = mfma16(K1, qf[0][1], mfma16(K0, qf[0][0], zero));
    S[1][0] = mfma16(K1, qf[1][1], mfma16(K0, qf[1][0], zero));
    S[0][1] = mfma16(K3, qf[0][1], mfma16(K2, qf[0][0], zero));
    S[1][1] = mfma16(K3, qf[1][1], mfma16(K2, qf[1][0], zero));
    #pragma unroll
    for (int s = 0; s < 2; ++s) {
        unsigned P0[2], P1[2];
        #pragma unroll
        for (int ct = 0; ct < 2; ++ct) {
            float e0 = __builtin_amdgcn_exp2f(S[s][ct][0] * LOG2E);
            float e1 = __builtin_amdgcn_exp2f(S[s][ct][1] * LOG2E);
            float e2 = __builtin_amdgcn_exp2f(S[s][ct][2] * LOG2E);
            float e3 = __builtin_amdgcn_exp2f(S[s][ct][3] * LOG2E);
            su[s] += (e0 + e1) + (e2 + e3);
            P0[ct] = pk2(e0, e1);
            P1[ct] = pk2(e2, e3);
        }
        union { uint4 u; bf16x8 f; } pf;
        pf.u.x = P0[0];
        pf.u.y = (unsigned)__shfl_xor((int)P1[0], 16);
        pf.u.z = P0[1];
        pf.u.w = (unsigned)__shfl_xor((int)P1[1], 16);
        #pragma unroll
        for (int dt = 0; dt < 4; ++dt) {
            bf16x8 vv = dt == 0 ? V0 : dt == 1 ? V1 : dt == 2 ? V2 : V3;
            oacc[s][dt] = mfma16(vv, pf.f, oacc[s][dt]);
        }
    }
}

// ---------------- main: barrier-free streaming attention ----------------
__global__ __launch_bounds__(256, 2)
void attn_stream(const float* __restrict__ q, const unsigned short* __restrict__ kws,
                 const unsigned short* __restrict__ vws, float* __restrict__ out) {
    const int t = threadIdx.x, lane = t & 63, w = t >> 6;
    const int n16 = lane & 15, quad = lane >> 4;
    const int bx = blockIdx.x;               // 512 blocks
    const int bh = bx & 63, qt = bx >> 6;    // XCD swizzle: same bh -> same bx%8
    const int h = bh & 15, b = bh >> 4;
    const int qbase = qt * 128 + w * 32;

    // Q B-frags: q = sub*16+n16, d = ks*32+quad*8+j, pre-scaled 1/8
    bf16x8 qf[2][2];
    #pragma unroll
    for (int s = 0; s < 2; ++s)
      #pragma unroll
      for (int ks = 0; ks < 2; ++ks) {
        const float* p = q + (((size_t)(b * SS + qbase + s * 16 + n16) * HH + h) * DD)
                           + ks * 32 + quad * 8;
        float4 x = ((const float4*)p)[0];
        float4 y = ((const float4*)p)[1];
        bf16x8 f;
        f[0] = (short)f2bf(x.x * 0.125f); f[1] = (short)f2bf(x.y * 0.125f);
        f[2] = (short)f2bf(x.z * 0.125f); f[3] = (short)f2bf(x.w * 0.125f);
        f[4] = (short)f2bf(y.x * 0.125f); f[5] = (short)f2bf(y.y * 0.125f);
        f[6] = (short)f2bf(y.z * 0.125f); f[7] = (short)f2bf(y.w * 0.125f);
        qf[s][ks] = f;
      }

    const unsigned short* kb  = kws + (size_t)bh * (SS * 64);
    const unsigned short* vb0 = vws + (size_t)bh * (64 * SS);
    const unsigned short* vb1 = vb0 + 16 * SS;
    const unsigned short* vb2 = vb0 + 32 * SS;
    const unsigned short* vb3 = vb0 + 48 * SS;

    f32x4 oacc[2][4];    // O^T: row d = dt*16+quad*4+r, col q = sub*16+n16
    #pragma unroll
    for (int s = 0; s < 2; ++s)
      #pragma unroll
      for (int dt = 0; dt < 4; ++dt) oacc[s][dt] = f32x4{0.f, 0.f, 0.f, 0.f};
    float su[2] = {0.f, 0.f};

    // per-lane byte offsets at kk=0
    const unsigned basek = ((unsigned)n16 << 7) | ((unsigned)quad << 4);
    const unsigned basev = ((unsigned)n16 << 11) | ((unsigned)quad << 4);

    bf16x8 Ka0, Ka1, Ka2, Ka3, Va0, Va1, Va2, Va3;
    bf16x8 Kb0, Kb1, Kb2, Kb3, Vb0, Vb1, Vb2, Vb3;

    ISSUE_KV(Ka0,Ka1,Ka2,Ka3,Va0,Va1,Va2,Va3, basek, basev)
    WAIT_KV(Ka0,Ka1,Ka2,Ka3,Va0,Va1,Va2,Va3)

    #pragma unroll 1
    for (int it = 0; it < 16; ++it) {
        const int kk1 = it * 64 + 32;                 // <= 992, no wrap
        const unsigned vk1 = basek + ((unsigned)kk1 << 7);
        const unsigned vv1 = basev + ((unsigned)kk1 << 1);
        ISSUE_KV(Kb0,Kb1,Kb2,Kb3,Vb0,Vb1,Vb2,Vb3, vk1, vv1)
        step32v(Ka0,Ka1,Ka2,Ka3,Va0,Va1,Va2,Va3, qf, oacc, su);
        WAIT_KV(Kb0,Kb1,Kb2,Kb3,Vb0,Vb1,Vb2,Vb3)

        const int kk2 = (it * 64 + 64) & 1023;        // wraps to 0 at it=15 (dead loads)
        const unsigned vk2 = basek + ((unsigned)kk2 << 7);
        const unsigned vv2 = basev + ((unsigned)kk2 << 1);
        ISSUE_KV(Ka0,Ka1,Ka2,Ka3,Va0,Va1,Va2,Va3, vk2, vv2)
        step32v(Kb0,Kb1,Kb2,Kb3,Vb0,Vb1,Vb2,Vb3, qf, oacc, su);
        WAIT_KV(Ka0,Ka1,Ka2,Ka3,Va0,Va1,Va2,Va3)
    }

    // epilogue: reduce su across quads (q lives on n16), normalize, store
    #pragma unroll
    for (int s = 0; s < 2; ++s) {
        su[s] += __shfl_xor(su[s], 16);
        su[s] += __shfl_xor(su[s], 32);
    }
    #pragma unroll
    for (int s = 0; s < 2; ++s) {
        float sc = 1.0f / su[s];     // clamps proven inactive; e^{-C'} cancels
        #pragma unroll
        for (int dt = 0; dt < 4; ++dt) {
            float4 val;
            val.x = oacc[s][dt][0] * sc;
            val.y = oacc[s][dt][1] * sc;
            val.z = oacc[s][dt][2] * sc;
            val.w = oacc[s][dt][3] * sc;
            size_t off = ((size_t)(b * SS + qbase + s * 16 + n16) * HH + h) * DD
                       + dt * 16 + quad * 4;
            *(float4*)&out[off] = val;
        }
    }
}

extern "C" void kernel_launch(void* const* d_in, const int* in_sizes, int n_in,
                              void* d_out, int out_size, void* d_ws, size_t ws_size,
                              hipStream_t stream) {
    const float* q = (const float*)d_in[0];
    const float* k = (const float*)d_in[1];
    const float* v = (const float*)d_in[2];
    float* o = (float*)d_out;
    unsigned short* kws = (unsigned short*)d_ws;                    // 8 MB
    unsigned short* vws = kws + (size_t)BB * HH * SS * DD;          // 8 MB
    hipLaunchKernelGGL(prep_kernel, dim3(1024), dim3(256), 0, stream, k, v, kws, vws);
    hipLaunchKernelGGL(attn_stream, dim3(512), dim3(256), 0, stream, q, kws, vws, o);
}

// Round 8
// 123.579 us; speedup vs baseline: 1.2826x; 1.2826x over previous
//
#include <hip/hip_runtime.h>

// B=4, S=1024, H=16, D=64 attention, clipped softmax.
// Round 8: r7's barrier-free streaming MFMA kernel, with workspace RE-TILED so
// every per-wave fragment load is one CONTIGUOUS 1 KB block (perfect L2
// channel/bank spread). r5/r6/r7 were pinned at 72us regardless of scheduling
// -> throughput serialization from power-of-2 lane strides (V: 2KB, K: 128B)
// concentrating each wave-load's 16 segments onto 1-2 L2 channels.
//   kws2: [c32][frag 0..3][n16][quad][8 d]   (1 KB per (c32,frag))
//   vws2: [c32][dt 0..3][quad][n16][8 keys]  (1 KB per (c32,dt))
// Same (row,d)->value placement as r7 -> MFMA operands bit-identical.
#define BB 4
#define SS 1024
#define HH 16
#define DD 64

typedef short bf16x8 __attribute__((ext_vector_type(8)));
typedef float f32x4 __attribute__((ext_vector_type(4)));

__device__ __forceinline__ unsigned pk2(float a, float b) {   // pack 2 bf16
    unsigned ua = __float_as_uint(a) + 0x8000u;
    unsigned ub = __float_as_uint(b) + 0x8000u;
    return (ub & 0xffff0000u) | (ua >> 16);
}
__device__ __forceinline__ unsigned short f2bf(float a) {
    return (unsigned short)((__float_as_uint(a) + 0x8000u) >> 16);
}
__device__ __forceinline__ f32x4 mfma16(bf16x8 a, bf16x8 b, f32x4 c) {
    return __builtin_amdgcn_mfma_f32_16x16x32_bf16(a, b, c, 0, 0, 0);
}
// sigma within 32-key chunks (verified r4/r5): pos x holds key ((q^(b>>1))<<3)|(a<<2)|b
__device__ __forceinline__ int sig5(int x) {
    int a = (x >> 4) & 1, qs = (x >> 2) & 3, b2 = x & 3;
    return ((qs ^ (b2 >> 1)) << 3) | (a << 2) | b2;
}

// ---------------- prep: K/V -> tiled-contiguous bf16 workspace ----------------
__global__ __launch_bounds__(256)
void prep_kernel(const float* __restrict__ k, const float* __restrict__ v,
                 unsigned short* __restrict__ kws, unsigned short* __restrict__ vws) {
    const int t = threadIdx.x;
    const int bx = blockIdx.x;
    if (bx < 512) {
        // K: thread handles permuted-position p = st*128 + row, d-half `half`
        const int bh = bx & 63, st = bx >> 6;
        const int h = bh & 15, b = bh >> 4;
        const int row = t >> 1, half = t & 1;
        const int p = st * 128 + row;
        const int key = (p & ~31) | sig5(p & 31);
        const float4* src = (const float4*)k + (((size_t)(b * SS + key) * HH + h) * 16) + half * 8;
        float4 r[8];
        #pragma unroll
        for (int i = 0; i < 8; ++i) r[i] = src[i];
        // dst: c32 = p/32, frag f = hi*2+half (hi = bit4 of row), lane n16 = p&15
        const int c32 = st * 4 + (row >> 5);
        const int f   = ((row >> 4) & 1) * 2 + half;
        const int n16k = row & 15;
        uint4* dst = (uint4*)(kws + (size_t)bh * 65536 + (size_t)((c32 * 4 + f) * 512 + n16k * 32));
        #pragma unroll
        for (int u = 0; u < 4; ++u) {
            uint4 val;
            val.x = pk2(r[2*u].x, r[2*u].y);
            val.y = pk2(r[2*u].z, r[2*u].w);
            val.z = pk2(r[2*u+1].x, r[2*u+1].y);
            val.w = pk2(r[2*u+1].z, r[2*u+1].w);
            dst[u] = val;
        }
    } else {
        // V: thread (o = key-octet 0..15, vc = d-group 0..15); no LDS needed.
        const int bx2 = bx - 512;
        const int bh = bx2 & 63, st = bx2 >> 6;
        const int h = bh & 15, b = bh >> 4;
        const int o = t >> 4, vc = t & 15;
        const float4* src = (const float4*)v + (((size_t)(b * SS + st * 128 + o * 8) * HH + h) * 16) + vc;
        float4 r[8];
        #pragma unroll
        for (int i = 0; i < 8; ++i) r[i] = src[(size_t)i * HH * 16];
        const float* fr = (const float*)r;
        const int c32 = st * 4 + (o >> 2);
        const int quad = o & 3;
        #pragma unroll
        for (int c = 0; c < 4; ++c) {
            const int d = 4 * vc + c;
            const int dt = d >> 4, n16v = d & 15;
            uint4 val;          // 8 keys (o*8..+7) at fixed d
            val.x = pk2(fr[0*4+c], fr[1*4+c]);
            val.y = pk2(fr[2*4+c], fr[3*4+c]);
            val.z = pk2(fr[4*4+c], fr[5*4+c]);
            val.w = pk2(fr[6*4+c], fr[7*4+c]);
            *(uint4*)(vws + (size_t)bh * 65536 +
                      (size_t)((c32 * 4 + dt) * 512 + quad * 128 + n16v * 8)) = val;
        }
    }
}

// issue 8 in-flight contiguous-1KB b128 loads for one 32-key step
#define ISSUE_KV(K0,K1,K2,K3,V0,V1,V2,V3, vk, vv)                                            \
  asm volatile("global_load_dwordx4 %0, %1, %2 offset:0"    : "=v"(K0) : "v"(vk), "s"(kb));  \
  asm volatile("global_load_dwordx4 %0, %1, %2 offset:1024" : "=v"(K1) : "v"(vk), "s"(kb));  \
  asm volatile("global_load_dwordx4 %0, %1, %2 offset:2048" : "=v"(K2) : "v"(vk), "s"(kb));  \
  asm volatile("global_load_dwordx4 %0, %1, %2 offset:3072" : "=v"(K3) : "v"(vk), "s"(kb));  \
  asm volatile("global_load_dwordx4 %0, %1, %2 offset:0"    : "=v"(V0) : "v"(vv), "s"(vbb)); \
  asm volatile("global_load_dwordx4 %0, %1, %2 offset:1024" : "=v"(V1) : "v"(vv), "s"(vbb)); \
  asm volatile("global_load_dwordx4 %0, %1, %2 offset:2048" : "=v"(V2) : "v"(vv), "s"(vbb)); \
  asm volatile("global_load_dwordx4 %0, %1, %2 offset:3072" : "=v"(V3) : "v"(vv), "s"(vbb));

// drain the batch; "+v" ties make every consumer data-dependent on this wait
#define WAIT_KV(K0,K1,K2,K3,V0,V1,V2,V3)                                  \
  asm volatile("s_waitcnt vmcnt(0)"                                       \
    : "+v"(K0),"+v"(K1),"+v"(K2),"+v"(K3),                                \
      "+v"(V0),"+v"(V1),"+v"(V2),"+v"(V3));

// compute one 32-key step: QK^T -> exp -> PV (all in registers)
__device__ __forceinline__ void step32v(bf16x8 K0, bf16x8 K1, bf16x8 K2, bf16x8 K3,
                                        bf16x8 V0, bf16x8 V1, bf16x8 V2, bf16x8 V3,
                                        const bf16x8 qf[2][2],
                                        f32x4 oacc[2][4], float su[2]) {
    const f32x4 zero = {0.f, 0.f, 0.f, 0.f};
    const float LOG2E = 1.44269504f;
    f32x4 S[2][2];
    S[0][0] = mfma16(K1, qf[0][1], mfma16(K0, qf[0][0], zero));
    S[1][0] = mfma16(K1, qf[1][1], mfma16(K0, qf[1][0], zero));
    S[0][1] = mfma16(K3, qf[0][1], mfma16(K2, qf[0][0], zero));
    S[1][1] = mfma16(K3, qf[1][1], mfma16(K2, qf[1][0], zero));
    #pragma unroll
    for (int s = 0; s < 2; ++s) {
        unsigned P0[2], P1[2];
        #pragma unroll
        for (int ct = 0; ct < 2; ++ct) {
            float e0 = __builtin_amdgcn_exp2f(S[s][ct][0] * LOG2E);
            float e1 = __builtin_amdgcn_exp2f(S[s][ct][1] * LOG2E);
            float e2 = __builtin_amdgcn_exp2f(S[s][ct][2] * LOG2E);
            float e3 = __builtin_amdgcn_exp2f(S[s][ct][3] * LOG2E);
            su[s] += (e0 + e1) + (e2 + e3);
            P0[ct] = pk2(e0, e1);
            P1[ct] = pk2(e2, e3);
        }
        union { uint4 u; bf16x8 f; } pf;
        pf.u.x = P0[0];
        pf.u.y = (unsigned)__shfl_xor((int)P1[0], 16);
        pf.u.z = P0[1];
        pf.u.w = (unsigned)__shfl_xor((int)P1[1], 16);
        #pragma unroll
        for (int dt = 0; dt < 4; ++dt) {
            bf16x8 vv = dt == 0 ? V0 : dt == 1 ? V1 : dt == 2 ? V2 : V3;
            oacc[s][dt] = mfma16(vv, pf.f, oacc[s][dt]);
        }
    }
}

// ---------------- main: barrier-free streaming attention ----------------
__global__ __launch_bounds__(256, 2)
void attn_stream(const float* __restrict__ q, const unsigned short* __restrict__ kws,
                 const unsigned short* __restrict__ vws, float* __restrict__ out) {
    const int t = threadIdx.x, lane = t & 63, w = t >> 6;
    const int n16 = lane & 15, quad = lane >> 4;
    const int bx = blockIdx.x;               // 512 blocks
    const int bh = bx & 63, qt = bx >> 6;    // XCD swizzle: same bh -> same bx%8
    const int h = bh & 15, b = bh >> 4;
    const int qbase = qt * 128 + w * 32;

    // Q B-frags: q = sub*16+n16, d = ks*32+quad*8+j, pre-scaled 1/8
    bf16x8 qf[2][2];
    #pragma unroll
    for (int s = 0; s < 2; ++s)
      #pragma unroll
      for (int ks = 0; ks < 2; ++ks) {
        const float* p = q + (((size_t)(b * SS + qbase + s * 16 + n16) * HH + h) * DD)
                           + ks * 32 + quad * 8;
        float4 x = ((const float4*)p)[0];
        float4 y = ((const float4*)p)[1];
        bf16x8 f;
        f[0] = (short)f2bf(x.x * 0.125f); f[1] = (short)f2bf(x.y * 0.125f);
        f[2] = (short)f2bf(x.z * 0.125f); f[3] = (short)f2bf(x.w * 0.125f);
        f[4] = (short)f2bf(y.x * 0.125f); f[5] = (short)f2bf(y.y * 0.125f);
        f[6] = (short)f2bf(y.z * 0.125f); f[7] = (short)f2bf(y.w * 0.125f);
        qf[s][ks] = f;
      }

    const unsigned short* kb  = kws + (size_t)bh * 65536;
    const unsigned short* vbb = vws + (size_t)bh * 65536;

    f32x4 oacc[2][4];    // O^T: row d = dt*16+quad*4+r, col q = sub*16+n16
    #pragma unroll
    for (int s = 0; s < 2; ++s)
      #pragma unroll
      for (int dt = 0; dt < 4; ++dt) oacc[s][dt] = f32x4{0.f, 0.f, 0.f, 0.f};
    float su[2] = {0.f, 0.f};

    // per-lane byte offsets inside each 4 KB step-chunk
    const unsigned basek = ((unsigned)n16 << 6) | ((unsigned)quad << 4);   // n16*64 + quad*16
    const unsigned basev = ((unsigned)quad << 8) | ((unsigned)n16 << 4);   // quad*256 + n16*16

    bf16x8 Ka0, Ka1, Ka2, Ka3, Va0, Va1, Va2, Va3;
    bf16x8 Kb0, Kb1, Kb2, Kb3, Vb0, Vb1, Vb2, Vb3;

    ISSUE_KV(Ka0,Ka1,Ka2,Ka3,Va0,Va1,Va2,Va3, basek, basev)
    WAIT_KV(Ka0,Ka1,Ka2,Ka3,Va0,Va1,Va2,Va3)

    #pragma unroll 1
    for (int it = 0; it < 16; ++it) {
        const unsigned c1 = (unsigned)(it * 2 + 1) << 12;          // c32 * 4096 B
        ISSUE_KV(Kb0,Kb1,Kb2,Kb3,Vb0,Vb1,Vb2,Vb3, basek + c1, basev + c1)
        step32v(Ka0,Ka1,Ka2,Ka3,Va0,Va1,Va2,Va3, qf, oacc, su);
        WAIT_KV(Kb0,Kb1,Kb2,Kb3,Vb0,Vb1,Vb2,Vb3)

        const unsigned c2 = (unsigned)((it * 2 + 2) & 31) << 12;   // wraps to 0 at it=15 (dead)
        ISSUE_KV(Ka0,Ka1,Ka2,Ka3,Va0,Va1,Va2,Va3, basek + c2, basev + c2)
        step32v(Kb0,Kb1,Kb2,Kb3,Vb0,Vb1,Vb2,Vb3, qf, oacc, su);
        WAIT_KV(Ka0,Ka1,Ka2,Ka3,Va0,Va1,Va2,Va3)
    }

    // epilogue: reduce su across quads (q lives on n16), normalize, store
    #pragma unroll
    for (int s = 0; s < 2; ++s) {
        su[s] += __shfl_xor(su[s], 16);
        su[s] += __shfl_xor(su[s], 32);
    }
    #pragma unroll
    for (int s = 0; s < 2; ++s) {
        float sc = 1.0f / su[s];     // clamps proven inactive; e^{-C'} cancels
        #pragma unroll
        for (int dt = 0; dt < 4; ++dt) {
            float4 val;
            val.x = oacc[s][dt][0] * sc;
            val.y = oacc[s][dt][1] * sc;
            val.z = oacc[s][dt][2] * sc;
            val.w = oacc[s][dt][3] * sc;
            size_t off = ((size_t)(b * SS + qbase + s * 16 + n16) * HH + h) * DD
                       + dt * 16 + quad * 4;
            *(float4*)&out[off] = val;
        }
    }
}

extern "C" void kernel_launch(void* const* d_in, const int* in_sizes, int n_in,
                              void* d_out, int out_size, void* d_ws, size_t ws_size,
                              hipStream_t stream) {
    const float* q = (const float*)d_in[0];
    const float* k = (const float*)d_in[1];
    const float* v = (const float*)d_in[2];
    float* o = (float*)d_out;
    unsigned short* kws = (unsigned short*)d_ws;                    // 8 MB
    unsigned short* vws = kws + (size_t)64 * 65536;                 // 8 MB
    hipLaunchKernelGGL(prep_kernel, dim3(1024), dim3(256), 0, stream, k, v, kws, vws);
    hipLaunchKernelGGL(attn_stream, dim3(512), dim3(256), 0, stream, q, kws, vws, o);
}